// Round 8
// baseline (1061.072 us; speedup 1.0000x reference)
//
#include <hip/hip_runtime.h>

// Char-LSTM (B=4096, T=40, H=256, V=128) on MI355X — weight-stationary v6.
//
// R7 post-mortem: NCS=16 doubled sc1 h-read amplification (32->64 MB/step,
// all forced to L3) -> L3-BW-bound, 796us despite 2x occupancy.
// R8 (single change vs R6's 598us): h exchange reads become CACHED loads,
// coherence via exactly ONE acquire (buffer_inv) per wave per step, issued
// AFTER the relaxed-poll group barrier completes. (R3/R4's mistake was an
// acquire-inv per poll ITERATION.) The 8 same-rg blocks share an XCD
// (bid%8==rg%8, perf-only) -> each h line: 1x L3 fetch + 7x L2 hits instead
// of 8x L3 sc1 reads. Producer stores stay relaxed-agent sc1 write-through
// (validated R5/R6). Correctness = release-to-L3 + acquire-inv: placement-
// independent. Numerics identical (3-pass split bf16, absmax 4.88e-4).

#define SEQ     40
#define VCH     128
#define HID     256
#define GATES   1024
#define NCS     8           // col-slices (128 packed cols = 32 units x 4 gates)
#define NBLK    256         // 8 cs x 32 rg
#define THREADS 512

typedef __attribute__((ext_vector_type(8))) short short8;   // 8 bf16
typedef __attribute__((ext_vector_type(4))) float f32x4;
typedef __attribute__((ext_vector_type(4))) unsigned int uint4v;

#define MFMA16(a, b, c) __builtin_amdgcn_mfma_f32_16x16x32_bf16((a), (b), (c), 0, 0, 0)

__device__ __forceinline__ unsigned short f2bf(float x) {
    unsigned u = __float_as_uint(x);
    return (unsigned short)((u + 0x7FFFu + ((u >> 16) & 1u)) >> 16);   // RNE
}
__device__ __forceinline__ float bf2f(unsigned short b) {
    return __uint_as_float(((unsigned)b) << 16);
}
__device__ __forceinline__ float sigm(float x) {
    return 1.0f / (1.0f + __expf(-x));
}
__device__ __forceinline__ float tanh_fast(float x) {
    float e = __expf(2.0f * x);
    return 1.0f - 2.0f / (e + 1.0f);
}

// ---------------------------------------------------------------------------
// ws layout (bytes):
//   Whi   ushort[262144] @ 0        (512 KB) packed: (((cs*8+f)*8+kc)*64+ln)*8+j
//   Wlo   ushort[262144] @ 512K     (512 KB)
//   Wdhi  ushort[32768]  @ 1024K    ( 64 KB)
//   Wdlo  ushort[32768]  @ 1088K    ( 64 KB)
//   Emb   float[131072]  @ 1152K    (512 KB) Emb[ch][pcol] = W_x[ch,oc]+b[oc]
//   hbuf  uint[2][4096*256] @ 1664K (8 MB)   ping-pong packed h (hi16|lo16)
//   barz  int[8224]      @ 10092544 (~33 KB) [32+b*32] = arrival flag block b
// ---------------------------------------------------------------------------

__global__ void pack_all(const float* __restrict__ W_lstm,
                         const float* __restrict__ b_lstm,
                         const float* __restrict__ W_dense,
                         unsigned short* __restrict__ Whi,
                         unsigned short* __restrict__ Wlo,
                         unsigned short* __restrict__ Wdhi,
                         unsigned short* __restrict__ Wdlo,
                         float* __restrict__ Emb,
                         int* __restrict__ barz) {
    int idx = blockIdx.x * blockDim.x + threadIdx.x;
    if (idx < 8224) barz[idx] = 0;
    if (idx < 262144) {
        // idx = (((cs*8+f)*8+kc)*64+lane)*8+j ; cs 0..7, f 0..7
        int j = idx & 7, lane = (idx >> 3) & 63, kc = (idx >> 9) & 7;
        int f = (idx >> 12) & 7, cs = idx >> 15;
        int oc = (f & 3) * 256 + cs * 32 + (f >> 2) * 16 + (lane & 15);
        int k  = kc * 32 + (lane >> 4) * 8 + j;
        float w = W_lstm[(size_t)(VCH + k) * GATES + oc];
        unsigned short hi = f2bf(w);
        Whi[idx] = hi;
        Wlo[idx] = f2bf(w - bf2f(hi));
    } else if (idx < 262144 + 32768) {
        int i2 = idx - 262144;
        int j = i2 & 7, lane = (i2 >> 3) & 63, kc = (i2 >> 9) & 7, f = i2 >> 12;
        int col = f * 16 + (lane & 15);
        int k   = kc * 32 + (lane >> 4) * 8 + j;
        float w = W_dense[(size_t)k * VCH + col];
        unsigned short hi = f2bf(w);
        Wdhi[i2] = hi;
        Wdlo[i2] = f2bf(w - bf2f(hi));
    } else if (idx < 262144 + 32768 + 131072) {
        int i3 = idx - (262144 + 32768);
        int pcol = i3 & 1023, ch = i3 >> 10;
        int cs = pcol >> 7, f = (pcol >> 4) & 7, n = pcol & 15;
        int oc = (f & 3) * 256 + cs * 32 + (f >> 2) * 16 + n;
        Emb[i3] = W_lstm[(size_t)ch * GATES + oc] + b_lstm[oc];
    }
}

// Leaderless 8-block group barrier + ONE acquire per wave on exit.
// Arrival: __syncthreads drains each wave's vmem (sc1 h stores reach L3),
// then RELEASE flag. Wait: threads 0..7 poll the group's 8 flags RELAXED
// (no invalidates). Exit: every thread does one ACQUIRE load -> one
// buffer_inv per wave -> subsequent CACHED h loads see fresh data.
__device__ __forceinline__ void groupbar(int* __restrict__ barz, int rg, int want) {
    __syncthreads();
    if (threadIdx.x == 0)
        __hip_atomic_store(&barz[32 + blockIdx.x * 32], want, __ATOMIC_RELEASE,
                           __HIP_MEMORY_SCOPE_AGENT);
    if (threadIdx.x < NCS) {
        while (__hip_atomic_load(&barz[32 + (threadIdx.x * 32 + rg) * 32],
                                 __ATOMIC_RELAXED, __HIP_MEMORY_SCOPE_AGENT) < want)
            __builtin_amdgcn_s_sleep(1);
    }
    __syncthreads();
    (void)__hip_atomic_load(&barz[32 + blockIdx.x * 32], __ATOMIC_ACQUIRE,
                            __HIP_MEMORY_SCOPE_AGENT);   // one buffer_inv / wave
}

__device__ __forceinline__ void unpack_a(uint4v u0, uint4v u1, short8& hi, short8& lo) {
    union { uint4v u; short8 s; } ch, cl;
    ch.u = (uint4v){ (u0[0] >> 16) | (u0[1] & 0xFFFF0000u),
                     (u0[2] >> 16) | (u0[3] & 0xFFFF0000u),
                     (u1[0] >> 16) | (u1[1] & 0xFFFF0000u),
                     (u1[2] >> 16) | (u1[3] & 0xFFFF0000u) };
    cl.u = (uint4v){ (u0[0] & 0xFFFFu) | (u0[1] << 16),
                     (u0[2] & 0xFFFFu) | (u0[3] << 16),
                     (u1[0] & 0xFFFFu) | (u1[1] << 16),
                     (u1[2] & 0xFFFFu) | (u1[3] << 16) };
    hi = ch.s;
    lo = cl.s;
}

__global__ __launch_bounds__(THREADS, 2)
void lstm_main(const int* __restrict__ inputs,
               const unsigned short* __restrict__ Whi,
               const unsigned short* __restrict__ Wlo,
               const unsigned short* __restrict__ Wdhi,
               const unsigned short* __restrict__ Wdlo,
               const float* __restrict__ Emb,
               const float* __restrict__ b_dense,
               unsigned int* __restrict__ hbuf,
               int* __restrict__ barz,
               float* __restrict__ out) {
    __shared__ __align__(16) unsigned short wsh[32768];   // 64 KB
    __shared__ __align__(16) unsigned short wsl[32768];   // 64 KB
    __shared__ unsigned char chs[SEQ * 128];              // 5 KB

    const int tid  = threadIdx.x;
    const int lane = tid & 63;
    const int w    = tid >> 6;
    const int n    = lane & 15;
    const int kq   = lane >> 4;
    const int cs   = blockIdx.x >> 5;      // col-slice 0..7
    const int rg   = blockIdx.x & 31;      // row-group 0..31 (barrier group)
    const int r0   = rg * 128;
    const int rw   = r0 + w * 16;

    // ---- stage weight slice + chars into LDS (one-time) -------------------
    {
        const uint4v* gh = (const uint4v*)(Whi + (size_t)cs * 32768);
        const uint4v* gl = (const uint4v*)(Wlo + (size_t)cs * 32768);
        uint4v* lh = (uint4v*)wsh;
        uint4v* ll = (uint4v*)wsl;
        for (int i = tid; i < 4096; i += THREADS) { lh[i] = gh[i]; ll[i] = gl[i]; }
    }
    for (int i = tid; i < SEQ * 128; i += THREADS) {
        int row = i & 127, t = i >> 7;
        chs[t * 128 + row] = (unsigned char)inputs[(size_t)(r0 + row) * SEQ + t];
    }
    // zero this block's slice of hbuf[0]
    for (int i = tid; i < 128 * 32; i += THREADS) {
        int rr = i >> 5, cc = i & 31;
        __hip_atomic_store(&hbuf[(size_t)(r0 + rr) * HID + cs * 32 + cc], 0u,
                           __ATOMIC_RELAXED, __HIP_MEMORY_SCOPE_AGENT);
    }

    float c_st[8];
#pragma unroll
    for (int i = 0; i < 8; ++i) c_st[i] = 0.0f;

    int gen = 1;
    groupbar(barz, rg, gen); gen++;   // group's hbuf[0] zeros at L3; LDS staged

    const float* embbase = Emb + cs * 128 + n;

#pragma unroll 1
    for (int t = 0; t < SEQ; ++t) {
        const unsigned int* hb = hbuf + (size_t)(t & 1) * 4096 * HID;
        unsigned int* hw = hbuf + (size_t)((t & 1) ^ 1) * 4096 * HID;

        // ---- A loads: CACHED (fresh after groupbar's buffer_inv) ----------
        const unsigned int* arow = hb + (size_t)(rw + n) * HID + kq * 8;
        uint4v araw[16];
#pragma unroll
        for (int kc = 0; kc < 8; ++kc) {
            araw[kc * 2]     = *(const uint4v*)(arow + kc * 32);
            araw[kc * 2 + 1] = *(const uint4v*)(arow + kc * 32 + 4);
        }

        // ---- emb gather for THIS step (cached; consumed post-MFMA) --------
        int ch[4];
#pragma unroll
        for (int r = 0; r < 4; ++r) ch[r] = chs[t * 128 + w * 16 + kq * 4 + r];
        float gv[8][4];
#pragma unroll
        for (int f = 0; f < 8; ++f)
#pragma unroll
            for (int r = 0; r < 4; ++r)
                gv[f][r] = embbase[(size_t)ch[r] * GATES + f * 16];

        // ---- 3-pass MFMA: z = h @ W_slice ---------------------------------
        f32x4 acc[8];
#pragma unroll
        for (int f = 0; f < 8; ++f) acc[f] = (f32x4){0.f, 0.f, 0.f, 0.f};
#pragma unroll
        for (int kc = 0; kc < 8; ++kc) {
            short8 ahi, alo;
            unpack_a(araw[kc * 2], araw[kc * 2 + 1], ahi, alo);
#pragma unroll
            for (int f = 0; f < 8; ++f) {
                short8 bh = *(const short8*)&wsh[(f * 8 + kc) * 512 + lane * 8];
                short8 bl = *(const short8*)&wsl[(f * 8 + kc) * 512 + lane * 8];
                acc[f] = MFMA16(ahi, bh, acc[f]);
                acc[f] = MFMA16(alo, bh, acc[f]);
                acc[f] = MFMA16(ahi, bl, acc[f]);
            }
        }

        // ---- in-register cell update; publish h (sc1 stores) --------------
        // lane owns (row = rw + kq*4 + r, unit = cs*32 + hf*16 + n)
#pragma unroll
        for (int hf = 0; hf < 2; ++hf) {
#pragma unroll
            for (int r = 0; r < 4; ++r) {
                float zi = acc[hf * 4 + 0][r] + gv[hf * 4 + 0][r];
                float zj = acc[hf * 4 + 1][r] + gv[hf * 4 + 1][r];
                float zf = acc[hf * 4 + 2][r] + gv[hf * 4 + 2][r];
                float zo = acc[hf * 4 + 3][r] + gv[hf * 4 + 3][r];
                float cc = sigm(zf + 1.0f) * c_st[hf * 4 + r]
                         + sigm(zi) * tanh_fast(zj);
                c_st[hf * 4 + r] = cc;
                float hh = sigm(zo) * tanh_fast(cc);
                unsigned short hi = f2bf(hh);
                unsigned short lo = f2bf(hh - bf2f(hi));
                unsigned int pk = ((unsigned int)hi << 16) | (unsigned int)lo;
                __hip_atomic_store(&hw[(size_t)(rw + kq * 4 + r) * HID + cs * 32 + hf * 16 + n],
                                   pk, __ATOMIC_RELAXED, __HIP_MEMORY_SCOPE_AGENT);
            }
        }

        groupbar(barz, rg, gen); gen++;
    }

    // ---- final dense: out[:, cs*16..+16] = h @ Wd + b (cached reads) ------
    {
        const unsigned int* arow = hbuf + (size_t)(rw + n) * HID + kq * 8;  // t=39 -> buf[0]
        f32x4 dacc = (f32x4){0.f, 0.f, 0.f, 0.f};
#pragma unroll
        for (int kc = 0; kc < 8; ++kc) {
            uint4v u0 = *(const uint4v*)(arow + kc * 32);
            uint4v u1 = *(const uint4v*)(arow + kc * 32 + 4);
            short8 ahi, alo;
            unpack_a(u0, u1, ahi, alo);
            short8 bh = *(const short8*)(Wdhi + (size_t)(cs * 8 + kc) * 512 + lane * 8);
            short8 bl = *(const short8*)(Wdlo + (size_t)(cs * 8 + kc) * 512 + lane * 8);
            dacc = MFMA16(ahi, bh, dacc);
            dacc = MFMA16(alo, bh, dacc);
            dacc = MFMA16(ahi, bl, dacc);
        }
        float bd = b_dense[cs * 16 + n];
#pragma unroll
        for (int r = 0; r < 4; ++r) {
            out[(size_t)(rw + kq * 4 + r) * VCH + cs * 16 + n] = dacc[r] + bd;
        }
    }
}

extern "C" void kernel_launch(void* const* d_in, const int* in_sizes, int n_in,
                              void* d_out, int out_size, void* d_ws, size_t ws_size,
                              hipStream_t stream) {
    const int*   inputs  = (const int*)d_in[0];
    const float* W_lstm  = (const float*)d_in[1];
    const float* b_lstm  = (const float*)d_in[2];
    const float* W_dense = (const float*)d_in[3];
    const float* b_dense = (const float*)d_in[4];
    float* out = (float*)d_out;

    char* ws = (char*)d_ws;
    unsigned short* Whi  = (unsigned short*)(ws);
    unsigned short* Wlo  = (unsigned short*)(ws + 524288);
    unsigned short* Wdhi = (unsigned short*)(ws + 1048576);
    unsigned short* Wdlo = (unsigned short*)(ws + 1114112);
    float*          Emb  = (float*)(ws + 1179648);
    unsigned int*   hbuf = (unsigned int*)(ws + 1703936);
    int*            barz = (int*)(ws + 1703936 + 8388608);

    const int total = 262144 + 32768 + 131072;
    hipLaunchKernelGGL(pack_all, dim3((total + 255) / 256), dim3(256), 0, stream,
                       W_lstm, b_lstm, W_dense, Whi, Wlo, Wdhi, Wdlo, Emb, barz);

    void* args[] = { (void*)&inputs, (void*)&Whi, (void*)&Wlo, (void*)&Wdhi,
                     (void*)&Wdlo, (void*)&Emb, (void*)&b_dense, (void*)&hbuf,
                     (void*)&barz, (void*)&out };
    hipError_t err = hipLaunchCooperativeKernel((const void*)lstm_main, dim3(NBLK),
                                                dim3(THREADS), args, 0, stream);
    if (err != hipSuccess) {
        hipLaunchKernelGGL(lstm_main, dim3(NBLK), dim3(THREADS), 0, stream,
                           inputs, Whi, Wlo, Wdhi, Wdlo, Emb, b_dense, hbuf, barz, out);
    }
}

// Round 9
// 442.087 us; speedup vs baseline: 2.4001x; 2.4001x over previous
//
#include <hip/hip_runtime.h>

// Char-LSTM (B=4096, T=40, H=256, V=128) on MI355X — weight-stationary v7.
//
// R8 post-mortem: ANY buffer_inv in the steady loop is poison (598->1032us).
// Rule: cross-block data via sc1 only; zero invalidates. Base = R6 (598us).
// R9: 1-pass bf16 numerics. h exchanged as bare bf16 (2B), W as RNE bf16.
//  * MFMA 192->64 per wave/step; LDS B-stream 1MB->256KB per CU/step;
//    A-loads 16->8 dwordx4/lane; no unpack VALU (A-frag = raw loaded bytes).
//  * hbuf unit order permuted (p = cs*32 + n*2 + hf <-> u = cs*32 + hf*16 + n)
//    so each lane's two h outputs pack into ONE u32 store; the matching
//    k-permutation is folded into the weight pack (ku from kp).
//  * fp32 kept: Emb/x-part, cell update, c state; dense = 2-pass split W.
// Exchange/barrier protocol identical to R6 (sc1 stores+loads, relaxed polls,
// release flags, leaderless 8-block groups, no invalidates).

#define SEQ     40
#define VCH     128
#define HID     256
#define GATES   1024
#define NCS     8           // col-slices (128 packed cols = 32 units x 4 gates)
#define NBLK    256         // 8 cs x 32 rg
#define THREADS 512

typedef __attribute__((ext_vector_type(8))) short short8;   // 8 bf16
typedef __attribute__((ext_vector_type(4))) float f32x4;
typedef __attribute__((ext_vector_type(4))) unsigned int uint4v;

#define MFMA16(a, b, c) __builtin_amdgcn_mfma_f32_16x16x32_bf16((a), (b), (c), 0, 0, 0)

__device__ __forceinline__ unsigned short f2bf(float x) {
    unsigned u = __float_as_uint(x);
    return (unsigned short)((u + 0x7FFFu + ((u >> 16) & 1u)) >> 16);   // RNE
}
__device__ __forceinline__ float bf2f(unsigned short b) {
    return __uint_as_float(((unsigned)b) << 16);
}
__device__ __forceinline__ float sigm(float x) {
    return 1.0f / (1.0f + __expf(-x));
}
__device__ __forceinline__ float tanh_fast(float x) {
    float e = __expf(2.0f * x);
    return 1.0f - 2.0f / (e + 1.0f);
}

// 16B load bypassing L1/L2 (sc1): L3-coherent view, no invalidates needed.
// Result valid only after s_waitcnt vmcnt(0) + sched_barrier(0).
__device__ __forceinline__ uint4v ld16_sc1(const unsigned int* p) {
    uint4v r;
    asm volatile("global_load_dwordx4 %0, %1, off sc1"
                 : "=&v"(r) : "v"(p) : "memory");
    return r;
}
__device__ __forceinline__ void vm_drain() {
    asm volatile("s_waitcnt vmcnt(0)" ::: "memory");
    __builtin_amdgcn_sched_barrier(0);
}

// hbuf physical position p (ushort in row) <-> logical unit u:
//   p = cs*32 + n*2 + hf   <->   u = cs*32 + hf*16 + n
// k-permutation for weight packs: packed k-pos kp reads logical unit
//   ku = (kp & ~31) | ((kp & 1) << 4) | ((kp >> 1) & 15)

// ---------------------------------------------------------------------------
// ws layout (bytes):
//   Whi   ushort[262144] @ 0        (512 KB) recurrent W bf16, frag-packed
//   (unused)            @ 512K     (512 KB)
//   Wdhi  ushort[32768]  @ 1024K    ( 64 KB) dense W hi
//   Wdlo  ushort[32768]  @ 1088K    ( 64 KB) dense W lo (residual)
//   Emb   float[131072]  @ 1152K    (512 KB) Emb[ch][pcol] = W_x[ch,oc]+b[oc]
//   hbuf  ushort[2][4096*256] @ 1664K (4 MB) ping-pong bf16 h (permuted units)
//   barz  int[8224]      @ 10092544 (~33 KB) [32+b*32] = arrival flag block b
// ---------------------------------------------------------------------------

__global__ void pack_all(const float* __restrict__ W_lstm,
                         const float* __restrict__ b_lstm,
                         const float* __restrict__ W_dense,
                         unsigned short* __restrict__ Whi,
                         unsigned short* __restrict__ Wdhi,
                         unsigned short* __restrict__ Wdlo,
                         float* __restrict__ Emb,
                         int* __restrict__ barz) {
    int idx = blockIdx.x * blockDim.x + threadIdx.x;
    if (idx < 8224) barz[idx] = 0;
    if (idx < 262144) {
        // idx = (((cs*8+f)*8+kc)*64+lane)*8+j ; cs 0..7, f 0..7
        int j = idx & 7, lane = (idx >> 3) & 63, kc = (idx >> 9) & 7;
        int f = (idx >> 12) & 7, cs = idx >> 15;
        int oc = (f & 3) * 256 + cs * 32 + (f >> 2) * 16 + (lane & 15);
        int kp = kc * 32 + (lane >> 4) * 8 + j;
        int ku = (kp & ~31) | ((kp & 1) << 4) | ((kp >> 1) & 15);
        Whi[idx] = f2bf(W_lstm[(size_t)(VCH + ku) * GATES + oc]);
    } else if (idx < 262144 + 32768) {
        int i2 = idx - 262144;
        int j = i2 & 7, lane = (i2 >> 3) & 63, kc = (i2 >> 9) & 7, f = i2 >> 12;
        int col = f * 16 + (lane & 15);
        int kp  = kc * 32 + (lane >> 4) * 8 + j;
        int ku  = (kp & ~31) | ((kp & 1) << 4) | ((kp >> 1) & 15);
        float w = W_dense[(size_t)ku * VCH + col];
        unsigned short hi = f2bf(w);
        Wdhi[i2] = hi;
        Wdlo[i2] = f2bf(w - bf2f(hi));
    } else if (idx < 262144 + 32768 + 131072) {
        int i3 = idx - (262144 + 32768);
        int pcol = i3 & 1023, ch = i3 >> 10;
        int cs = pcol >> 7, f = (pcol >> 4) & 7, n = pcol & 15;
        int oc = (f & 3) * 256 + cs * 32 + (f >> 2) * 16 + n;
        Emb[i3] = W_lstm[(size_t)ch * GATES + oc] + b_lstm[oc];
    }
}

// Leaderless 8-block group barrier (blocks {c*32+rg, c=0..7}), zero
// invalidates (R6-validated). Top __syncthreads drains each wave's vmem
// (sc1 h stores reach L3) before the RELEASE flag; threads 0..7 poll the
// group's 8 flags RELAXED; post-barrier h reads are sc1 -> no stale cache.
__device__ __forceinline__ void groupbar(int* __restrict__ barz, int rg, int want) {
    __syncthreads();
    if (threadIdx.x == 0)
        __hip_atomic_store(&barz[32 + blockIdx.x * 32], want, __ATOMIC_RELEASE,
                           __HIP_MEMORY_SCOPE_AGENT);
    if (threadIdx.x < NCS) {
        while (__hip_atomic_load(&barz[32 + (threadIdx.x * 32 + rg) * 32],
                                 __ATOMIC_RELAXED, __HIP_MEMORY_SCOPE_AGENT) < want)
            __builtin_amdgcn_s_sleep(1);
    }
    __syncthreads();
}

__global__ __launch_bounds__(THREADS, 2)
void lstm_main(const int* __restrict__ inputs,
               const unsigned short* __restrict__ Whi,
               const unsigned short* __restrict__ Wdhi,
               const unsigned short* __restrict__ Wdlo,
               const float* __restrict__ Emb,
               const float* __restrict__ b_dense,
               unsigned int* __restrict__ hbu32,   // u32 view of bf16 hbuf
               int* __restrict__ barz,
               float* __restrict__ out) {
    __shared__ __align__(16) unsigned short wsh[32768];   // 64 KB W slice
    __shared__ unsigned char chs[SEQ * 128];              // 5 KB

    const int tid  = threadIdx.x;
    const int lane = tid & 63;
    const int w    = tid >> 6;
    const int n    = lane & 15;
    const int kq   = lane >> 4;
    const int cs   = blockIdx.x >> 5;      // col-slice 0..7
    const int rg   = blockIdx.x & 31;      // row-group 0..31 (barrier group)
    const int r0   = rg * 128;
    const int rw   = r0 + w * 16;

    // ---- stage weight slice + chars into LDS (one-time) -------------------
    {
        const uint4v* gh = (const uint4v*)(Whi + (size_t)cs * 32768);
        uint4v* lh = (uint4v*)wsh;
        for (int i = tid; i < 4096; i += THREADS) lh[i] = gh[i];
    }
    for (int i = tid; i < SEQ * 128; i += THREADS) {
        int row = i & 127, t = i >> 7;
        chs[t * 128 + row] = (unsigned char)inputs[(size_t)(r0 + row) * SEQ + t];
    }
    // zero this block's slice of hbuf[0] (u32 cols cs*16..+16 per row)
    for (int i = tid; i < 128 * 16; i += THREADS) {
        int rr = i >> 4, cc = i & 15;
        __hip_atomic_store(&hbu32[(size_t)(r0 + rr) * 128 + cs * 16 + cc], 0u,
                           __ATOMIC_RELAXED, __HIP_MEMORY_SCOPE_AGENT);
    }

    float c_st[8];
#pragma unroll
    for (int i = 0; i < 8; ++i) c_st[i] = 0.0f;

    int gen = 1;
    groupbar(barz, rg, gen); gen++;   // group's hbuf[0] zeros at L3; LDS staged

    const float* embbase = Emb + cs * 128 + n;

#pragma unroll 1
    for (int t = 0; t < SEQ; ++t) {
        const unsigned int* hb = hbu32 + (size_t)(t & 1) * 4096 * 128;
        unsigned int* hw = hbu32 + (size_t)((t & 1) ^ 1) * 4096 * 128;

        // ---- A loads: 8x dwordx4 sc1 = this lane's 8 bf16 x 8 kc ----------
        const unsigned int* arow = hb + (size_t)(rw + n) * 128 + kq * 4;
        uint4v araw[8];
#pragma unroll
        for (int kc = 0; kc < 8; ++kc)
            araw[kc] = ld16_sc1(arow + kc * 16);
        vm_drain();

        // ---- emb gather for THIS step (cached; consumed post-MFMA) --------
        int ch[4];
#pragma unroll
        for (int r = 0; r < 4; ++r) ch[r] = chs[t * 128 + w * 16 + kq * 4 + r];
        float gv[8][4];
#pragma unroll
        for (int f = 0; f < 8; ++f)
#pragma unroll
            for (int r = 0; r < 4; ++r)
                gv[f][r] = embbase[(size_t)ch[r] * GATES + f * 16];

        // ---- 1-pass MFMA: z = h @ W_slice (64 MFMAs/wave) -----------------
        f32x4 acc[8];
#pragma unroll
        for (int f = 0; f < 8; ++f) acc[f] = (f32x4){0.f, 0.f, 0.f, 0.f};
#pragma unroll
        for (int kc = 0; kc < 8; ++kc) {
            union { uint4v u; short8 s; } av; av.u = araw[kc];
#pragma unroll
            for (int f = 0; f < 8; ++f) {
                short8 bh = *(const short8*)&wsh[(f * 8 + kc) * 512 + lane * 8];
                acc[f] = MFMA16(av.s, bh, acc[f]);
            }
        }

        // ---- in-register cell update; publish h (one u32 sc1 store/row) ---
        // lane owns (row = rw + kq*4 + r, units cs*32 + {0,16} + n)
#pragma unroll
        for (int r = 0; r < 4; ++r) {
            unsigned int pk = 0;
#pragma unroll
            for (int hf = 0; hf < 2; ++hf) {
                float zi = acc[hf * 4 + 0][r] + gv[hf * 4 + 0][r];
                float zj = acc[hf * 4 + 1][r] + gv[hf * 4 + 1][r];
                float zf = acc[hf * 4 + 2][r] + gv[hf * 4 + 2][r];
                float zo = acc[hf * 4 + 3][r] + gv[hf * 4 + 3][r];
                float cc = sigm(zf + 1.0f) * c_st[hf * 4 + r]
                         + sigm(zi) * tanh_fast(zj);
                c_st[hf * 4 + r] = cc;
                float hh = sigm(zo) * tanh_fast(cc);
                pk |= (unsigned int)f2bf(hh) << (hf * 16);
            }
            __hip_atomic_store(&hw[(size_t)(rw + kq * 4 + r) * 128 + cs * 16 + n],
                               pk, __ATOMIC_RELAXED, __HIP_MEMORY_SCOPE_AGENT);
        }

        groupbar(barz, rg, gen); gen++;
    }

    // ---- final dense: out[:, cs*16..+16] = h @ Wd + b (2-pass split W) ----
    {
        const unsigned int* arow = hbu32 + (size_t)(rw + n) * 128 + kq * 4;  // t=39 -> buf[0]
        uint4v draw[8];
#pragma unroll
        for (int kc = 0; kc < 8; ++kc)
            draw[kc] = ld16_sc1(arow + kc * 16);
        vm_drain();
        f32x4 dacc = (f32x4){0.f, 0.f, 0.f, 0.f};
#pragma unroll
        for (int kc = 0; kc < 8; ++kc) {
            union { uint4v u; short8 s; } av; av.u = draw[kc];
            short8 bh = *(const short8*)(Wdhi + (size_t)(cs * 8 + kc) * 512 + lane * 8);
            short8 bl = *(const short8*)(Wdlo + (size_t)(cs * 8 + kc) * 512 + lane * 8);
            dacc = MFMA16(av.s, bh, dacc);
            dacc = MFMA16(av.s, bl, dacc);
        }
        float bd = b_dense[cs * 16 + n];
#pragma unroll
        for (int r = 0; r < 4; ++r) {
            out[(size_t)(rw + kq * 4 + r) * VCH + cs * 16 + n] = dacc[r] + bd;
        }
    }
}

extern "C" void kernel_launch(void* const* d_in, const int* in_sizes, int n_in,
                              void* d_out, int out_size, void* d_ws, size_t ws_size,
                              hipStream_t stream) {
    const int*   inputs  = (const int*)d_in[0];
    const float* W_lstm  = (const float*)d_in[1];
    const float* b_lstm  = (const float*)d_in[2];
    const float* W_dense = (const float*)d_in[3];
    const float* b_dense = (const float*)d_in[4];
    float* out = (float*)d_out;

    char* ws = (char*)d_ws;
    unsigned short* Whi  = (unsigned short*)(ws);
    unsigned short* Wdhi = (unsigned short*)(ws + 1048576);
    unsigned short* Wdlo = (unsigned short*)(ws + 1114112);
    float*          Emb  = (float*)(ws + 1179648);
    unsigned int*   hbu  = (unsigned int*)(ws + 1703936);
    int*            barz = (int*)(ws + 1703936 + 8388608);

    const int total = 262144 + 32768 + 131072;
    hipLaunchKernelGGL(pack_all, dim3((total + 255) / 256), dim3(256), 0, stream,
                       W_lstm, b_lstm, W_dense, Whi, Wdhi, Wdlo, Emb, barz);

    void* args[] = { (void*)&inputs, (void*)&Whi, (void*)&Wdhi, (void*)&Wdlo,
                     (void*)&Emb, (void*)&b_dense, (void*)&hbu,
                     (void*)&barz, (void*)&out };
    hipError_t err = hipLaunchCooperativeKernel((const void*)lstm_main, dim3(NBLK),
                                                dim3(THREADS), args, 0, stream);
    if (err != hipSuccess) {
        hipLaunchKernelGGL(lstm_main, dim3(NBLK), dim3(THREADS), 0, stream,
                           inputs, Whi, Wdhi, Wdlo, Emb, b_dense, hbu, barz, out);
    }
}